// Round 7
// baseline (934.780 us; speedup 1.0000x reference)
//
#include <hip/hip_runtime.h>
#include <math.h>

#define N_NODES 50000
#define N_EDGES 800000
#define F_IN    128
#define HID     256
#define BN_EPS  1e-5f
#define SCAN_BLOCKS ((N_NODES + 255) / 256)   // 196

typedef unsigned int uint;
typedef __attribute__((ext_vector_type(8))) short bf16x8;  // 8 bf16 = 4 VGPRs
typedef __attribute__((ext_vector_type(4))) float f32x4;

__device__ __forceinline__ float bf2f(unsigned short u) {
    return __uint_as_float((uint)u << 16);
}
__device__ __forceinline__ unsigned short f2bf(float f) {   // RTNE
    uint u = __float_as_uint(f);
    return (unsigned short)((u + 0x7FFFu + ((u >> 16) & 1u)) >> 16);
}

// ---------------------------------------------------------------- CSR build
__global__ void hist_kernel(const int* __restrict__ dst, int* __restrict__ deg) {
    int e = blockIdx.x * blockDim.x + threadIdx.x;
    if (e < N_EDGES) atomicAdd(&deg[dst[e]], 1);
}

__global__ __launch_bounds__(256) void scan1_kernel(const int* __restrict__ deg,
                                                    int* __restrict__ row_ptr,
                                                    int* __restrict__ partials) {
    __shared__ int sm[256];
    int i = blockIdx.x * 256 + threadIdx.x;
    int v = (i < N_NODES) ? deg[i] : 0;
    sm[threadIdx.x] = v;
    __syncthreads();
    for (int off = 1; off < 256; off <<= 1) {
        int t = (threadIdx.x >= off) ? sm[threadIdx.x - off] : 0;
        __syncthreads();
        sm[threadIdx.x] += t;
        __syncthreads();
    }
    if (i < N_NODES) row_ptr[i] = sm[threadIdx.x] - v;   // tile-local exclusive
    if (threadIdx.x == 255) partials[blockIdx.x] = sm[255];
}

__global__ __launch_bounds__(256) void scan2_kernel(int* __restrict__ partials) {
    __shared__ int sm[256];
    int t = threadIdx.x;
    int v = (t < SCAN_BLOCKS) ? partials[t] : 0;
    sm[t] = v;
    __syncthreads();
    for (int off = 1; off < 256; off <<= 1) {
        int p = (t >= off) ? sm[t - off] : 0;
        __syncthreads();
        sm[t] += p;
        __syncthreads();
    }
    if (t < SCAN_BLOCKS) partials[t] = sm[t] - v;        // exclusive base
}

__global__ __launch_bounds__(256) void scan3_kernel(int* __restrict__ row_ptr,
                                                    int* __restrict__ cursor,
                                                    const int* __restrict__ partials) {
    int i = blockIdx.x * 256 + threadIdx.x;
    if (i < N_NODES) {
        int v = row_ptr[i] + partials[blockIdx.x];
        row_ptr[i] = v;
        cursor[i]  = v;
    }
    if (i == 0) row_ptr[N_NODES] = N_EDGES;
}

__global__ void fill_kernel(const int* __restrict__ src, const int* __restrict__ dst,
                            int* __restrict__ cursor, int* __restrict__ csr_src) {
    int e = blockIdx.x * blockDim.x + threadIdx.x;
    if (e >= N_EDGES) return;
    int pos = atomicAdd(&cursor[dst[e]], 1);
    csr_src[pos] = src[e];
}

// ---------------------------------------------------------------- cast x -> bf16
__global__ void cast_bf16_kernel(const float* __restrict__ x, unsigned short* __restrict__ xb,
                                 int total4) {
    int i = blockIdx.x * blockDim.x + threadIdx.x;
    if (i >= total4) return;
    float4 v = *(const float4*)&x[(long)i * 4];
    unsigned short o[4] = {f2bf(v.x), f2bf(v.y), f2bf(v.z), f2bf(v.w)};
    *(uint2*)&xb[(long)i * 4] = *(const uint2*)o;
}

// ---------------------------------------------------------------- weight pack
// PB fragment-major: idx = ((t*KS + s)*4 + q)*128 + n16*8 + j
// value = W[k = s*32+q*8+j][n = t*16+n16], W = [Wn ; Wr] (k<K1 -> Wn)
__global__ void pack_b_kernel(const float* __restrict__ Wn, const float* __restrict__ Wr,
                              int K1, int KS, unsigned short* __restrict__ PB) {
    int idx = blockIdx.x * 256 + threadIdx.x;
    int per_t = KS * 512;
    int t = idx / per_t, rem = idx % per_t;
    int s = rem >> 9;
    int r2 = rem & 511;
    int q = r2 >> 7, n16 = (r2 >> 3) & 15, j = r2 & 7;
    int k = s * 32 + q * 8 + j, n = t * 16 + n16;
    float v = (k < K1) ? Wn[k * HID + n] : Wr[(k - K1) * HID + n];
    PB[idx] = f2bf(v);
}

// ---------------------------------------------------------------- gather-mean (bf16)
template<int D>
__global__ __launch_bounds__(256) void gather_mean_kernel(
    const unsigned short* __restrict__ x, const int* __restrict__ row_ptr,
    const int* __restrict__ csr_src, unsigned short* __restrict__ agg) {
    constexpr int VPL = D / 64;                 // 2 (D=128) or 4 (D=256)
    int node = blockIdx.x * 4 + (threadIdx.x >> 6);
    int lane = threadIdx.x & 63;
    if (node >= N_NODES) return;
    int beg = row_ptr[node], end = row_ptr[node + 1];
    float acc[VPL];
#pragma unroll
    for (int j = 0; j < VPL; j++) acc[j] = 0.f;
    int e = beg;
    for (; e + 4 <= end; e += 4) {
        int s0 = csr_src[e], s1 = csr_src[e + 1], s2 = csr_src[e + 2], s3 = csr_src[e + 3];
        if constexpr (VPL == 4) {
            uint2 v0 = *(const uint2*)&x[(long)s0 * D + lane * 4];
            uint2 v1 = *(const uint2*)&x[(long)s1 * D + lane * 4];
            uint2 v2 = *(const uint2*)&x[(long)s2 * D + lane * 4];
            uint2 v3 = *(const uint2*)&x[(long)s3 * D + lane * 4];
            acc[0] += (bf2f((unsigned short)(v0.x & 0xFFFF)) + bf2f((unsigned short)(v1.x & 0xFFFF)))
                    + (bf2f((unsigned short)(v2.x & 0xFFFF)) + bf2f((unsigned short)(v3.x & 0xFFFF)));
            acc[1] += (bf2f((unsigned short)(v0.x >> 16))    + bf2f((unsigned short)(v1.x >> 16)))
                    + (bf2f((unsigned short)(v2.x >> 16))    + bf2f((unsigned short)(v3.x >> 16)));
            acc[2] += (bf2f((unsigned short)(v0.y & 0xFFFF)) + bf2f((unsigned short)(v1.y & 0xFFFF)))
                    + (bf2f((unsigned short)(v2.y & 0xFFFF)) + bf2f((unsigned short)(v3.y & 0xFFFF)));
            acc[3] += (bf2f((unsigned short)(v0.y >> 16))    + bf2f((unsigned short)(v1.y >> 16)))
                    + (bf2f((unsigned short)(v2.y >> 16))    + bf2f((unsigned short)(v3.y >> 16)));
        } else {
            uint v0 = *(const uint*)&x[(long)s0 * D + lane * 2];
            uint v1 = *(const uint*)&x[(long)s1 * D + lane * 2];
            uint v2 = *(const uint*)&x[(long)s2 * D + lane * 2];
            uint v3 = *(const uint*)&x[(long)s3 * D + lane * 2];
            acc[0] += (bf2f((unsigned short)(v0 & 0xFFFF)) + bf2f((unsigned short)(v1 & 0xFFFF)))
                    + (bf2f((unsigned short)(v2 & 0xFFFF)) + bf2f((unsigned short)(v3 & 0xFFFF)));
            acc[1] += (bf2f((unsigned short)(v0 >> 16))    + bf2f((unsigned short)(v1 >> 16)))
                    + (bf2f((unsigned short)(v2 >> 16))    + bf2f((unsigned short)(v3 >> 16)));
        }
    }
    for (; e < end; e++) {
        int s0 = csr_src[e];
        if constexpr (VPL == 4) {
            uint2 v0 = *(const uint2*)&x[(long)s0 * D + lane * 4];
            acc[0] += bf2f((unsigned short)(v0.x & 0xFFFF));
            acc[1] += bf2f((unsigned short)(v0.x >> 16));
            acc[2] += bf2f((unsigned short)(v0.y & 0xFFFF));
            acc[3] += bf2f((unsigned short)(v0.y >> 16));
        } else {
            uint v0 = *(const uint*)&x[(long)s0 * D + lane * 2];
            acc[0] += bf2f((unsigned short)(v0 & 0xFFFF));
            acc[1] += bf2f((unsigned short)(v0 >> 16));
        }
    }
    float inv = 1.0f / fmaxf((float)(end - beg), 1.0f);
    unsigned short* o = &agg[(long)node * D + lane * VPL];
    if constexpr (VPL == 4) {
        unsigned short ov[4] = {f2bf(acc[0] * inv), f2bf(acc[1] * inv),
                                f2bf(acc[2] * inv), f2bf(acc[3] * inv)};
        *(uint2*)o = *(const uint2*)ov;
    } else {
        unsigned short ov[2] = {f2bf(acc[0] * inv), f2bf(acc[1] * inv)};
        *(uint*)o = *(const uint*)ov;
    }
}

// ---------------------------------------------------------------- MFMA GEMM + BN stats
// Barrier-free, LDS-free: one wave owns 32 rows x 128 cols; A/B fragments
// loaded directly from global (B pre-packed fragment-major, 1 KB/wave/load).
// Register double-buffer over KS fully-unrolled K-steps.
template<int K1, int K2>
__global__ __launch_bounds__(256) void mfma_gemm_kernel(
    const unsigned short* __restrict__ A1, const unsigned short* __restrict__ A2,
    const unsigned short* __restrict__ PB, const float* __restrict__ bias,
    unsigned short* __restrict__ Hout, float* __restrict__ s12) {
    constexpr int KT = K1 + K2;
    constexpr int KS = KT / 32;
    constexpr int RT = (N_NODES + 31) / 32;   // 1563 row-tiles
    const int gw   = blockIdx.x * 4 + (threadIdx.x >> 6);
    const int lane = threadIdx.x & 63;
    const int row_tile = gw >> 1;
    const int col_half = gw & 1;
    if (row_tile >= RT) return;
    const int r0   = row_tile * 32;
    const int n16  = lane & 15;
    const int quad = lane >> 4;
    const long arow0 = min(r0 + n16, N_NODES - 1);
    const long arow1 = min(r0 + 16 + n16, N_NODES - 1);
    const unsigned short* pb = PB + (long)col_half * 8 * KS * 512 + quad * 128 + n16 * 8;

    f32x4 acc[2][8];
#pragma unroll
    for (int mt = 0; mt < 2; mt++)
#pragma unroll
        for (int nt = 0; nt < 8; nt++) acc[mt][nt] = (f32x4){0.f, 0.f, 0.f, 0.f};

    bf16x8 a[2][2], b[2][8];
    auto loadstep = [&](int s, bf16x8* ab, bf16x8* bb) {
        const unsigned short* Ab;
        int pitch, kk;
        if (s * 32 < K1) { Ab = A1; pitch = K1; kk = s * 32; }
        else             { Ab = A2; pitch = K2; kk = s * 32 - K1; }
        ab[0] = *(const bf16x8*)&Ab[arow0 * pitch + kk + quad * 8];
        ab[1] = *(const bf16x8*)&Ab[arow1 * pitch + kk + quad * 8];
#pragma unroll
        for (int nt = 0; nt < 8; nt++)
            bb[nt] = *(const bf16x8*)&pb[((long)nt * KS + s) * 512];
    };
    loadstep(0, a[0], b[0]);
#pragma unroll
    for (int s = 0; s < KS; ++s) {
        int cur = s & 1;
        if (s + 1 < KS) loadstep(s + 1, a[cur ^ 1], b[cur ^ 1]);
#pragma unroll
        for (int mt = 0; mt < 2; mt++)
#pragma unroll
            for (int nt = 0; nt < 8; nt++)
                acc[mt][nt] = __builtin_amdgcn_mfma_f32_16x16x32_bf16(
                    a[cur][mt], b[cur][nt], acc[mt][nt], 0, 0, 0);
    }

    // epilogue: C/D col=lane&15 (n16), row=quad*4+reg; fused BN stats
    const int colbase = col_half * 128;
#pragma unroll
    for (int nt = 0; nt < 8; nt++) {
        int col = colbase + nt * 16 + n16;
        float bv = bias[col];
        float ssum = 0.f, qsum = 0.f;
#pragma unroll
        for (int mt = 0; mt < 2; mt++) {
#pragma unroll
            for (int reg = 0; reg < 4; reg++) {
                int row = r0 + mt * 16 + quad * 4 + reg;
                float v = acc[mt][nt][reg] + bv;
                if (row < N_NODES) {
                    Hout[(long)row * HID + col] = f2bf(v);
                    ssum += v;
                    qsum += v * v;
                }
            }
        }
        ssum += __shfl_xor(ssum, 16, 64);
        ssum += __shfl_xor(ssum, 32, 64);
        qsum += __shfl_xor(qsum, 16, 64);
        qsum += __shfl_xor(qsum, 32, 64);
        if (quad == 0) {
            atomicAdd(&s12[col], ssum);
            atomicAdd(&s12[HID + col], qsum);
        }
    }
}

// ---------------------------------------------------------------- BN + ELU
template<bool OUT32>
__global__ void bn_elu_kernel(const unsigned short* __restrict__ h, const float* __restrict__ s12,
                              const float* __restrict__ g, const float* __restrict__ b,
                              void* __restrict__ out) {
    const int total4 = N_NODES * HID / 4;
    int i = blockIdx.x * blockDim.x + threadIdx.x;
    if (i >= total4) return;
    int c4 = (i % (HID / 4)) * 4;
    uint2 v = *(const uint2*)&h[(long)i * 4];
    float in[4] = {bf2f((unsigned short)(v.x & 0xFFFF)), bf2f((unsigned short)(v.x >> 16)),
                   bf2f((unsigned short)(v.y & 0xFFFF)), bf2f((unsigned short)(v.y >> 16))};
    float o[4];
#pragma unroll
    for (int j = 0; j < 4; j++) {
        int c = c4 + j;
        float mu  = s12[c] * (1.0f / N_NODES);
        float var = s12[HID + c] * (1.0f / N_NODES) - mu * mu;
        var = fmaxf(var, 0.f);
        float inv = rsqrtf(var + BN_EPS);
        float t = (in[j] - mu) * inv * g[c] + b[c];
        o[j] = t > 0.f ? t : expm1f(t);
    }
    if (OUT32) {
        float4 ov = {o[0], o[1], o[2], o[3]};
        *(float4*)&((float*)out)[(long)i * 4] = ov;
    } else {
        unsigned short ov[4] = {f2bf(o[0]), f2bf(o[1]), f2bf(o[2]), f2bf(o[3])};
        *(uint2*)&((unsigned short*)out)[(long)i * 4] = *(const uint2*)ov;
    }
}

// ---------------------------------------------------------------- launch
extern "C" void kernel_launch(void* const* d_in, const int* in_sizes, int n_in,
                              void* d_out, int out_size, void* d_ws, size_t ws_size,
                              hipStream_t stream) {
    const float* x   = (const float*)d_in[0];
    const int*   ei  = (const int*)d_in[1];
    const int*   src = ei;
    const int*   dst = ei + N_EDGES;
    const float* Wn[3] = {(const float*)d_in[2],  (const float*)d_in[7],  (const float*)d_in[12]};
    const float* bn[3] = {(const float*)d_in[3],  (const float*)d_in[8],  (const float*)d_in[13]};
    const float* Wr[3] = {(const float*)d_in[4],  (const float*)d_in[9],  (const float*)d_in[14]};
    const float* g [3] = {(const float*)d_in[5],  (const float*)d_in[10], (const float*)d_in[15]};
    const float* b [3] = {(const float*)d_in[6],  (const float*)d_in[11], (const float*)d_in[16]};
    float* out = (float*)d_out;

    const size_t BF = (size_t)N_NODES * HID * 2;   // 25.6 MB (bf16 N x 256)
    char* ws = (char*)d_ws;
    unsigned short* B0  = (unsigned short*)(ws);                  // agg bf16
    unsigned short* B1  = (unsigned short*)(ws + BF);             // gemm out bf16
    unsigned short* B2  = (unsigned short*)(ws + 2 * BF);         // activations bf16
    unsigned short* XB  = (unsigned short*)(ws + 3 * BF);         // x bf16 [N,128] 12.8 MB
    char* ws2 = ws + 3 * BF + (size_t)N_NODES * F_IN * 2;
    unsigned short* PB0 = (unsigned short*)(ws2);                 // 16*8*512 shorts
    unsigned short* PB1 = (unsigned short*)(ws2 + 16 * 8 * 512 * 2);
    unsigned short* PB2 = (unsigned short*)(ws2 + 16 * 8 * 512 * 2 + 16 * 16 * 512 * 2);
    char* ws3 = ws2 + 16 * 8 * 512 * 2 + 2 * (16 * 16 * 512 * 2);
    int*   row_ptr = (int*)ws3;
    int*   cursor  = row_ptr + (N_NODES + 1);
    int*   deg_i   = cursor + N_NODES;
    int*   partial = deg_i + N_NODES;
    int*   csr_src = partial + SCAN_BLOCKS;
    float* s12     = (float*)(csr_src + N_EDGES);

    const int eb = (N_EDGES + 255) / 256;
    const int gather_blocks = (N_NODES + 3) / 4;
    const int elu_blocks = (N_NODES * HID / 4 + 255) / 256;
    const int gemm_blocks = (((N_NODES + 31) / 32) * 2 + 3) / 4;   // 782

    // ---------------- one-time per call: CSR + bf16 weights/x
    hipMemsetAsync(deg_i, 0, N_NODES * sizeof(int), stream);
    hist_kernel<<<eb, 256, 0, stream>>>(dst, deg_i);
    scan1_kernel<<<SCAN_BLOCKS, 256, 0, stream>>>(deg_i, row_ptr, partial);
    scan2_kernel<<<1, 256, 0, stream>>>(partial);
    scan3_kernel<<<SCAN_BLOCKS, 256, 0, stream>>>(row_ptr, cursor, partial);
    fill_kernel<<<eb, 256, 0, stream>>>(src, dst, cursor, csr_src);
    cast_bf16_kernel<<<(N_NODES * F_IN / 4 + 255) / 256, 256, 0, stream>>>(x, XB, N_NODES * F_IN / 4);
    pack_b_kernel<<<16 * 8 * 512 / 256, 256, 0, stream>>>(Wn[0], Wr[0], F_IN, 8, PB0);
    pack_b_kernel<<<16 * 16 * 512 / 256, 256, 0, stream>>>(Wn[1], Wr[1], HID, 16, PB1);
    pack_b_kernel<<<16 * 16 * 512 / 256, 256, 0, stream>>>(Wn[2], Wr[2], HID, 16, PB2);

    // ---------------- layer 0: XB[N,128] -> act B2
    gather_mean_kernel<F_IN><<<gather_blocks, 256, 0, stream>>>(XB, row_ptr, csr_src, B0);
    hipMemsetAsync(s12, 0, 2 * HID * sizeof(float), stream);
    mfma_gemm_kernel<F_IN, F_IN><<<gemm_blocks, 256, 0, stream>>>(B0, XB, PB0, bn[0], B1, s12);
    bn_elu_kernel<false><<<elu_blocks, 256, 0, stream>>>(B1, s12, g[0], b[0], B2);

    // ---------------- layer 1: B2 -> act B2
    gather_mean_kernel<HID><<<gather_blocks, 256, 0, stream>>>(B2, row_ptr, csr_src, B0);
    hipMemsetAsync(s12, 0, 2 * HID * sizeof(float), stream);
    mfma_gemm_kernel<HID, HID><<<gemm_blocks, 256, 0, stream>>>(B0, B2, PB1, bn[1], B1, s12);
    bn_elu_kernel<false><<<elu_blocks, 256, 0, stream>>>(B1, s12, g[1], b[1], B2);

    // ---------------- layer 2: B2 -> out (fp32)
    gather_mean_kernel<HID><<<gather_blocks, 256, 0, stream>>>(B2, row_ptr, csr_src, B0);
    hipMemsetAsync(s12, 0, 2 * HID * sizeof(float), stream);
    mfma_gemm_kernel<HID, HID><<<gemm_blocks, 256, 0, stream>>>(B0, B2, PB2, bn[2], B1, s12);
    bn_elu_kernel<true><<<elu_blocks, 256, 0, stream>>>(B1, s12, g[2], b[2], out);
}

// Round 8
// 667.366 us; speedup vs baseline: 1.4007x; 1.4007x over previous
//
#include <hip/hip_runtime.h>
#include <math.h>

#define N_NODES 50000
#define N_EDGES 800000
#define F_IN    128
#define HID     256
#define BN_EPS  1e-5f
#define SCAN_BLOCKS ((N_NODES + 255) / 256)   // 196

typedef unsigned int uint;
typedef __attribute__((ext_vector_type(8))) short bf16x8;  // 8 bf16 = 4 VGPRs
typedef __attribute__((ext_vector_type(4))) float f32x4;

__device__ __forceinline__ float bf2f(unsigned short u) {
    return __uint_as_float((uint)u << 16);
}
__device__ __forceinline__ unsigned short f2bf(float f) {   // RTNE
    uint u = __float_as_uint(f);
    return (unsigned short)((u + 0x7FFFu + ((u >> 16) & 1u)) >> 16);
}

// async global->LDS, 16B per lane; LDS dest = wave-uniform base + lane*16
__device__ __forceinline__ void gload16(const unsigned short* g, unsigned short* l) {
    __builtin_amdgcn_global_load_lds(
        (const __attribute__((address_space(1))) void*)g,
        (__attribute__((address_space(3))) void*)l, 16, 0, 0);
}

// ---------------------------------------------------------------- CSR build
__global__ void hist_kernel(const int* __restrict__ dst, int* __restrict__ deg) {
    int e = blockIdx.x * blockDim.x + threadIdx.x;
    if (e < N_EDGES) atomicAdd(&deg[dst[e]], 1);
}

__global__ __launch_bounds__(256) void scan1_kernel(const int* __restrict__ deg,
                                                    int* __restrict__ row_ptr,
                                                    int* __restrict__ partials) {
    __shared__ int sm[256];
    int i = blockIdx.x * 256 + threadIdx.x;
    int v = (i < N_NODES) ? deg[i] : 0;
    sm[threadIdx.x] = v;
    __syncthreads();
    for (int off = 1; off < 256; off <<= 1) {
        int t = (threadIdx.x >= off) ? sm[threadIdx.x - off] : 0;
        __syncthreads();
        sm[threadIdx.x] += t;
        __syncthreads();
    }
    if (i < N_NODES) row_ptr[i] = sm[threadIdx.x] - v;   // tile-local exclusive
    if (threadIdx.x == 255) partials[blockIdx.x] = sm[255];
}

__global__ __launch_bounds__(256) void scan2_kernel(int* __restrict__ partials) {
    __shared__ int sm[256];
    int t = threadIdx.x;
    int v = (t < SCAN_BLOCKS) ? partials[t] : 0;
    sm[t] = v;
    __syncthreads();
    for (int off = 1; off < 256; off <<= 1) {
        int p = (t >= off) ? sm[t - off] : 0;
        __syncthreads();
        sm[t] += p;
        __syncthreads();
    }
    if (t < SCAN_BLOCKS) partials[t] = sm[t] - v;        // exclusive base
}

__global__ __launch_bounds__(256) void scan3_kernel(int* __restrict__ row_ptr,
                                                    int* __restrict__ cursor,
                                                    const int* __restrict__ partials) {
    int i = blockIdx.x * 256 + threadIdx.x;
    if (i < N_NODES) {
        int v = row_ptr[i] + partials[blockIdx.x];
        row_ptr[i] = v;
        cursor[i]  = v;
    }
    if (i == 0) row_ptr[N_NODES] = N_EDGES;
}

__global__ void fill_kernel(const int* __restrict__ src, const int* __restrict__ dst,
                            int* __restrict__ cursor, int* __restrict__ csr_src) {
    int e = blockIdx.x * blockDim.x + threadIdx.x;
    if (e >= N_EDGES) return;
    int pos = atomicAdd(&cursor[dst[e]], 1);
    csr_src[pos] = src[e];
}

// ---------------------------------------------------------------- cast x -> bf16
__global__ void cast_bf16_kernel(const float* __restrict__ x, unsigned short* __restrict__ xb,
                                 int total4) {
    int i = blockIdx.x * blockDim.x + threadIdx.x;
    if (i >= total4) return;
    float4 v = *(const float4*)&x[(long)i * 4];
    unsigned short o[4] = {f2bf(v.x), f2bf(v.y), f2bf(v.z), f2bf(v.w)};
    *(uint2*)&xb[(long)i * 4] = *(const uint2*)o;
}

// ---------------------------------------------------------------- weight transpose
// WT[n][k] bf16, k < K1 from Wn[k][n], else Wr[k-K1][n]
__global__ void wt_kernel(const float* __restrict__ Wn, const float* __restrict__ Wr,
                          int K1, int KT, unsigned short* __restrict__ WT) {
    int k = blockIdx.x;     // 0..KT-1
    int n = threadIdx.x;    // 0..255
    float v = (k < K1) ? Wn[k * HID + n] : Wr[(k - K1) * HID + n];
    WT[(long)n * KT + k] = f2bf(v);
}

// ---------------------------------------------------------------- gather-mean (bf16)
template<int D>
__global__ __launch_bounds__(256) void gather_mean_kernel(
    const unsigned short* __restrict__ x, const int* __restrict__ row_ptr,
    const int* __restrict__ csr_src, unsigned short* __restrict__ agg) {
    constexpr int VPL = D / 64;                 // 2 (D=128) or 4 (D=256)
    int node = blockIdx.x * 4 + (threadIdx.x >> 6);
    int lane = threadIdx.x & 63;
    if (node >= N_NODES) return;
    int beg = row_ptr[node], end = row_ptr[node + 1];
    float acc[VPL];
#pragma unroll
    for (int j = 0; j < VPL; j++) acc[j] = 0.f;
    int e = beg;
    for (; e + 4 <= end; e += 4) {
        int s0 = csr_src[e], s1 = csr_src[e + 1], s2 = csr_src[e + 2], s3 = csr_src[e + 3];
        if constexpr (VPL == 4) {
            uint2 v0 = *(const uint2*)&x[(long)s0 * D + lane * 4];
            uint2 v1 = *(const uint2*)&x[(long)s1 * D + lane * 4];
            uint2 v2 = *(const uint2*)&x[(long)s2 * D + lane * 4];
            uint2 v3 = *(const uint2*)&x[(long)s3 * D + lane * 4];
            acc[0] += (bf2f((unsigned short)(v0.x & 0xFFFF)) + bf2f((unsigned short)(v1.x & 0xFFFF)))
                    + (bf2f((unsigned short)(v2.x & 0xFFFF)) + bf2f((unsigned short)(v3.x & 0xFFFF)));
            acc[1] += (bf2f((unsigned short)(v0.x >> 16))    + bf2f((unsigned short)(v1.x >> 16)))
                    + (bf2f((unsigned short)(v2.x >> 16))    + bf2f((unsigned short)(v3.x >> 16)));
            acc[2] += (bf2f((unsigned short)(v0.y & 0xFFFF)) + bf2f((unsigned short)(v1.y & 0xFFFF)))
                    + (bf2f((unsigned short)(v2.y & 0xFFFF)) + bf2f((unsigned short)(v3.y & 0xFFFF)));
            acc[3] += (bf2f((unsigned short)(v0.y >> 16))    + bf2f((unsigned short)(v1.y >> 16)))
                    + (bf2f((unsigned short)(v2.y >> 16))    + bf2f((unsigned short)(v3.y >> 16)));
        } else {
            uint v0 = *(const uint*)&x[(long)s0 * D + lane * 2];
            uint v1 = *(const uint*)&x[(long)s1 * D + lane * 2];
            uint v2 = *(const uint*)&x[(long)s2 * D + lane * 2];
            uint v3 = *(const uint*)&x[(long)s3 * D + lane * 2];
            acc[0] += (bf2f((unsigned short)(v0 & 0xFFFF)) + bf2f((unsigned short)(v1 & 0xFFFF)))
                    + (bf2f((unsigned short)(v2 & 0xFFFF)) + bf2f((unsigned short)(v3 & 0xFFFF)));
            acc[1] += (bf2f((unsigned short)(v0 >> 16))    + bf2f((unsigned short)(v1 >> 16)))
                    + (bf2f((unsigned short)(v2 >> 16))    + bf2f((unsigned short)(v3 >> 16)));
        }
    }
    for (; e < end; e++) {
        int s0 = csr_src[e];
        if constexpr (VPL == 4) {
            uint2 v0 = *(const uint2*)&x[(long)s0 * D + lane * 4];
            acc[0] += bf2f((unsigned short)(v0.x & 0xFFFF));
            acc[1] += bf2f((unsigned short)(v0.x >> 16));
            acc[2] += bf2f((unsigned short)(v0.y & 0xFFFF));
            acc[3] += bf2f((unsigned short)(v0.y >> 16));
        } else {
            uint v0 = *(const uint*)&x[(long)s0 * D + lane * 2];
            acc[0] += bf2f((unsigned short)(v0 & 0xFFFF));
            acc[1] += bf2f((unsigned short)(v0 >> 16));
        }
    }
    float inv = 1.0f / fmaxf((float)(end - beg), 1.0f);
    unsigned short* o = &agg[(long)node * D + lane * VPL];
    if constexpr (VPL == 4) {
        unsigned short ov[4] = {f2bf(acc[0] * inv), f2bf(acc[1] * inv),
                                f2bf(acc[2] * inv), f2bf(acc[3] * inv)};
        *(uint2*)o = *(const uint2*)ov;
    } else {
        unsigned short ov[2] = {f2bf(acc[0] * inv), f2bf(acc[1] * inv)};
        *(uint*)o = *(const uint*)ov;
    }
}

// ---------------------------------------------------------------- MFMA GEMM + BN stats
// m97-style K-loop: global_load_lds width-16 staging into un-padded LDS tiles,
// XOR-swizzled chunk order (applied on the GLOBAL pointer side) so ds_read_b128
// frag reads are bank-balanced. Block = 128 rows x 128 cols; wave = 32 rows x 128.
template<int K1, int K2>
__global__ __launch_bounds__(256) void mfma_gemm_kernel(
    const unsigned short* __restrict__ A1, const unsigned short* __restrict__ A2,
    const unsigned short* __restrict__ WT, const float* __restrict__ bias,
    unsigned short* __restrict__ Hout, float* __restrict__ s12) {
    constexpr int KT = K1 + K2;
    constexpr int NITER = KT / 64;
    __shared__ unsigned short As[128 * 64];   // 16 KB [row][64k], chunk-swizzled
    __shared__ unsigned short Bs[128 * 64];   // 16 KB [n]  [64k], chunk-swizzled
    __shared__ float cs[128];
    __shared__ float cq[128];

    const int tid  = threadIdx.x;
    const int wave = tid >> 6;
    const int lane = tid & 63;
    const int m16  = lane & 15;
    const int quad = lane >> 4;
    const int row_block = blockIdx.x >> 1;
    const int col_half  = blockIdx.x & 1;
    const int r0 = row_block * 128;
    const int rl = lane >> 3;                 // staging: row within 8-group
    const int cl = lane & 7;                  // staging: logical chunk
    const int csw = cl ^ rl;                  // swizzled chunk fetched by this lane

    if (tid < 128) { cs[tid] = 0.f; cq[tid] = 0.f; }

    f32x4 acc[2][8];
#pragma unroll
    for (int mt = 0; mt < 2; mt++)
#pragma unroll
        for (int nt = 0; nt < 8; nt++) acc[mt][nt] = (f32x4){0.f, 0.f, 0.f, 0.f};

    for (int k0 = 0; k0 < KT; k0 += 64) {
        const unsigned short* Ab;
        int pitch, kk;
        if (k0 < K1) { Ab = A1; pitch = K1; kk = k0; }
        else         { Ab = A2; pitch = K2; kk = k0 - K1; }
        // stage A: wave w covers rows w*32..w*32+31 (4 insts of 8 rows)
#pragma unroll
        for (int j = 0; j < 4; ++j) {
            int lr = wave * 32 + j * 8 + rl;
            long gr = min(r0 + lr, N_NODES - 1);
            gload16(&Ab[gr * pitch + kk + csw * 8], &As[(wave * 32 + j * 8) * 64]);
        }
        // stage B: same shape from WT rows (cols of H)
#pragma unroll
        for (int j = 0; j < 4; ++j) {
            int lr = wave * 32 + j * 8 + rl;
            long gn = col_half * 128 + lr;
            gload16(&WT[gn * KT + k0 + csw * 8], &Bs[(wave * 32 + j * 8) * 64]);
        }
        __syncthreads();
#pragma unroll
        for (int ks = 0; ks < 2; ++ks) {
            bf16x8 afrag[2], bfrag[8];
#pragma unroll
            for (int mt = 0; mt < 2; mt++) {
                int ar = wave * 32 + mt * 16 + m16;
                afrag[mt] = *(const bf16x8*)&As[ar * 64 + (((ks * 4 + quad) ^ (m16 & 7)) * 8)];
            }
#pragma unroll
            for (int nt = 0; nt < 8; nt++) {
                int br = nt * 16 + m16;
                bfrag[nt] = *(const bf16x8*)&Bs[br * 64 + (((ks * 4 + quad) ^ (m16 & 7)) * 8)];
            }
#pragma unroll
            for (int mt = 0; mt < 2; mt++)
#pragma unroll
                for (int nt = 0; nt < 8; nt++)
                    acc[mt][nt] = __builtin_amdgcn_mfma_f32_16x16x32_bf16(
                        afrag[mt], bfrag[nt], acc[mt][nt], 0, 0, 0);
        }
        __syncthreads();
    }

    // epilogue: C/D layout col=lane&15, row=quad*4+reg; fused BN stats
#pragma unroll
    for (int nt = 0; nt < 8; nt++) {
        int lcol = nt * 16 + m16;
        int col  = col_half * 128 + lcol;
        float bv = bias[col];
        float s = 0.f, q = 0.f;
#pragma unroll
        for (int mt = 0; mt < 2; mt++) {
#pragma unroll
            for (int reg = 0; reg < 4; reg++) {
                int row = r0 + wave * 32 + mt * 16 + quad * 4 + reg;
                float v = acc[mt][nt][reg] + bv;
                if (row < N_NODES) {
                    Hout[(long)row * HID + col] = f2bf(v);
                    s += v;
                    q += v * v;
                }
            }
        }
        atomicAdd(&cs[lcol], s);
        atomicAdd(&cq[lcol], q);
    }
    __syncthreads();
    if (tid < 128) {
        atomicAdd(&s12[col_half * 128 + tid], cs[tid]);
        atomicAdd(&s12[HID + col_half * 128 + tid], cq[tid]);
    }
}

// ---------------------------------------------------------------- BN + ELU
template<bool OUT32>
__global__ void bn_elu_kernel(const unsigned short* __restrict__ h, const float* __restrict__ s12,
                              const float* __restrict__ g, const float* __restrict__ b,
                              void* __restrict__ out) {
    const int total4 = N_NODES * HID / 4;
    int i = blockIdx.x * blockDim.x + threadIdx.x;
    if (i >= total4) return;
    int c4 = (i % (HID / 4)) * 4;
    uint2 v = *(const uint2*)&h[(long)i * 4];
    float in[4] = {bf2f((unsigned short)(v.x & 0xFFFF)), bf2f((unsigned short)(v.x >> 16)),
                   bf2f((unsigned short)(v.y & 0xFFFF)), bf2f((unsigned short)(v.y >> 16))};
    float o[4];
#pragma unroll
    for (int j = 0; j < 4; j++) {
        int c = c4 + j;
        float mu  = s12[c] * (1.0f / N_NODES);
        float var = s12[HID + c] * (1.0f / N_NODES) - mu * mu;
        var = fmaxf(var, 0.f);
        float inv = rsqrtf(var + BN_EPS);
        float t = (in[j] - mu) * inv * g[c] + b[c];
        o[j] = t > 0.f ? t : expm1f(t);
    }
    if (OUT32) {
        float4 ov = {o[0], o[1], o[2], o[3]};
        *(float4*)&((float*)out)[(long)i * 4] = ov;
    } else {
        unsigned short ov[4] = {f2bf(o[0]), f2bf(o[1]), f2bf(o[2]), f2bf(o[3])};
        *(uint2*)&((unsigned short*)out)[(long)i * 4] = *(const uint2*)ov;
    }
}

// ---------------------------------------------------------------- launch
extern "C" void kernel_launch(void* const* d_in, const int* in_sizes, int n_in,
                              void* d_out, int out_size, void* d_ws, size_t ws_size,
                              hipStream_t stream) {
    const float* x   = (const float*)d_in[0];
    const int*   ei  = (const int*)d_in[1];
    const int*   src = ei;
    const int*   dst = ei + N_EDGES;
    const float* Wn[3] = {(const float*)d_in[2],  (const float*)d_in[7],  (const float*)d_in[12]};
    const float* bn[3] = {(const float*)d_in[3],  (const float*)d_in[8],  (const float*)d_in[13]};
    const float* Wr[3] = {(const float*)d_in[4],  (const float*)d_in[9],  (const float*)d_in[14]};
    const float* g [3] = {(const float*)d_in[5],  (const float*)d_in[10], (const float*)d_in[15]};
    const float* b [3] = {(const float*)d_in[6],  (const float*)d_in[11], (const float*)d_in[16]};
    float* out = (float*)d_out;

    const size_t BF = (size_t)N_NODES * HID * 2;   // 25.6 MB (bf16 N x 256)
    char* ws = (char*)d_ws;
    unsigned short* B0  = (unsigned short*)(ws);                  // agg bf16
    unsigned short* B1  = (unsigned short*)(ws + BF);             // gemm out bf16
    unsigned short* B2  = (unsigned short*)(ws + 2 * BF);         // activations bf16
    unsigned short* XB  = (unsigned short*)(ws + 3 * BF);         // x bf16 [N,128] 12.8 MB
    char* ws2 = ws + 3 * BF + (size_t)N_NODES * F_IN * 2;
    unsigned short* WT0 = (unsigned short*)(ws2);                 // [256][256]
    unsigned short* WT1 = (unsigned short*)(ws2 + 256 * 256 * 2); // [256][512]
    unsigned short* WT2 = (unsigned short*)(ws2 + 256 * 256 * 2 + 256 * 512 * 2);
    char* ws3 = ws2 + 256 * 256 * 2 + 2 * (256 * 512 * 2);
    int*   row_ptr = (int*)ws3;
    int*   cursor  = row_ptr + (N_NODES + 1);
    int*   deg_i   = cursor + N_NODES;
    int*   partial = deg_i + N_NODES;
    int*   csr_src = partial + SCAN_BLOCKS;
    float* s12     = (float*)(csr_src + N_EDGES);

    const int eb = (N_EDGES + 255) / 256;
    const int gather_blocks = (N_NODES + 3) / 4;
    const int elu_blocks = (N_NODES * HID / 4 + 255) / 256;
    const int gemm_blocks = ((N_NODES + 127) / 128) * 2;   // 391 * 2 = 782

    // ---------------- one-time per call: CSR + bf16 weights/x
    hipMemsetAsync(deg_i, 0, N_NODES * sizeof(int), stream);
    hist_kernel<<<eb, 256, 0, stream>>>(dst, deg_i);
    scan1_kernel<<<SCAN_BLOCKS, 256, 0, stream>>>(deg_i, row_ptr, partial);
    scan2_kernel<<<1, 256, 0, stream>>>(partial);
    scan3_kernel<<<SCAN_BLOCKS, 256, 0, stream>>>(row_ptr, cursor, partial);
    fill_kernel<<<eb, 256, 0, stream>>>(src, dst, cursor, csr_src);
    cast_bf16_kernel<<<(N_NODES * F_IN / 4 + 255) / 256, 256, 0, stream>>>(x, XB, N_NODES * F_IN / 4);
    wt_kernel<<<256, 256, 0, stream>>>(Wn[0], Wr[0], F_IN, 2 * F_IN, WT0);
    wt_kernel<<<512, 256, 0, stream>>>(Wn[1], Wr[1], HID, 2 * HID, WT1);
    wt_kernel<<<512, 256, 0, stream>>>(Wn[2], Wr[2], HID, 2 * HID, WT2);

    // ---------------- layer 0: XB[N,128] -> act B2
    gather_mean_kernel<F_IN><<<gather_blocks, 256, 0, stream>>>(XB, row_ptr, csr_src, B0);
    hipMemsetAsync(s12, 0, 2 * HID * sizeof(float), stream);
    mfma_gemm_kernel<F_IN, F_IN><<<gemm_blocks, 256, 0, stream>>>(B0, XB, WT0, bn[0], B1, s12);
    bn_elu_kernel<false><<<elu_blocks, 256, 0, stream>>>(B1, s12, g[0], b[0], B2);

    // ---------------- layer 1: B2 -> act B2
    gather_mean_kernel<HID><<<gather_blocks, 256, 0, stream>>>(B2, row_ptr, csr_src, B0);
    hipMemsetAsync(s12, 0, 2 * HID * sizeof(float), stream);
    mfma_gemm_kernel<HID, HID><<<gemm_blocks, 256, 0, stream>>>(B0, B2, WT1, bn[1], B1, s12);
    bn_elu_kernel<false><<<elu_blocks, 256, 0, stream>>>(B1, s12, g[1], b[1], B2);

    // ---------------- layer 2: B2 -> out (fp32)
    gather_mean_kernel<HID><<<gather_blocks, 256, 0, stream>>>(B2, row_ptr, csr_src, B0);
    hipMemsetAsync(s12, 0, 2 * HID * sizeof(float), stream);
    mfma_gemm_kernel<HID, HID><<<gemm_blocks, 256, 0, stream>>>(B0, B2, WT2, bn[2], B1, s12);
    bn_elu_kernel<true><<<elu_blocks, 256, 0, stream>>>(B1, s12, g[2], b[2], out);
}